// Round 1
// baseline (7851.353 us; speedup 1.0000x reference)
//
#include <hip/hip_runtime.h>
#include <hip/hip_bf16.h>

// Problem constants (match reference setup_inputs)
#define N_USER 50000
#define N_ITEM 50000
#define NNODE  100000          // N_USER + N_ITEM
#define D_LAT  64
#define D_HID  256             // 4 * D_LAT
#define D_FEAT 1280
#define NEDGE  4000000         // directed edges

// ---------------- degree / dinv ----------------
__global__ void k_count_deg(const int* __restrict__ rows, int* __restrict__ cnt, int E) {
    int i = blockIdx.x * blockDim.x + threadIdx.x;
    int stride = gridDim.x * blockDim.x;
    for (; i < E; i += stride) atomicAdd(&cnt[rows[i]], 1);
}

__global__ void k_dinv(const int* __restrict__ cnt, float* __restrict__ dinv, int n) {
    int i = blockIdx.x * blockDim.x + threadIdx.x;
    if (i < n) {
        int c = cnt[i];
        dinv[i] = (c > 0) ? rsqrtf((float)c) : 0.0f;
    }
}

// ---------------- fp32 tiled GEMM with bias (+ optional leaky-relu) ----------------
// C[(row_off+m)*Nn + n] = act(sum_k A[m*K+k] * B[k*Nn+n] + bias[n])
template<bool LRELU>
__global__ void k_gemm_bias(const float* __restrict__ A, const float* __restrict__ B,
                            const float* __restrict__ bias, float* __restrict__ C,
                            int M, int K, int Nn, int row_off) {
    const int BM = 64, BN = 64, BK = 16;
    __shared__ float As[BK][BM + 1];
    __shared__ float Bs[BK][BN + 1];
    const int t  = threadIdx.x;            // 256 threads
    const int tx = t & 15;
    const int ty = t >> 4;
    const int bm = blockIdx.y * BM;
    const int bn = blockIdx.x * BN;

    float acc[4][4] = {};

    for (int k0 = 0; k0 < K; k0 += BK) {
        // Load A tile: 64 rows x 16 k. thread -> (kk = t&15, mm = t>>4), 4 row-passes
        {
            const int kk = t & 15;
            const int mm = t >> 4;
            #pragma unroll
            for (int p = 0; p < 4; ++p) {
                int r = bm + mm + p * 16;
                float v = 0.0f;
                if (r < M) v = A[(long)r * K + k0 + kk];
                As[kk][mm + p * 16] = v;
            }
        }
        // Load B tile: 16 k x 64 n. thread -> (nn = t&63, kk = t>>6), 4 k-passes
        {
            const int nn = t & 63;
            const int kb = t >> 6;
            #pragma unroll
            for (int p = 0; p < 4; ++p) {
                Bs[kb + p * 4][nn] = B[(long)(k0 + kb + p * 4) * Nn + bn + nn];
            }
        }
        __syncthreads();
        #pragma unroll
        for (int kk = 0; kk < BK; ++kk) {
            float a[4], b[4];
            #pragma unroll
            for (int i = 0; i < 4; ++i) a[i] = As[kk][ty * 4 + i];
            #pragma unroll
            for (int j = 0; j < 4; ++j) b[j] = Bs[kk][tx * 4 + j];
            #pragma unroll
            for (int i = 0; i < 4; ++i)
                #pragma unroll
                for (int j = 0; j < 4; ++j)
                    acc[i][j] += a[i] * b[j];
        }
        __syncthreads();
    }

    #pragma unroll
    for (int i = 0; i < 4; ++i) {
        int r = bm + ty * 4 + i;
        if (r >= M) continue;
        #pragma unroll
        for (int j = 0; j < 4; ++j) {
            int n = bn + tx * 4 + j;
            float v = acc[i][j] + bias[n];
            if (LRELU) v = (v > 0.0f) ? v : 0.01f * v;
            C[(long)(row_off + r) * Nn + n] = v;
        }
    }
}

// ---------------- row normalize (64 lanes per row) ----------------
__global__ void k_normalize(float* __restrict__ x, int nrows) {
    int row  = blockIdx.x * (blockDim.x >> 6) + (threadIdx.x >> 6);
    int lane = threadIdx.x & 63;
    if (row >= nrows) return;
    float v = x[row * 64 + lane];
    float ss = v * v;
    #pragma unroll
    for (int off = 32; off > 0; off >>= 1) ss += __shfl_xor(ss, off, 64);
    float norm = sqrtf(ss);
    float scale = 1.0f / fmaxf(norm, 1e-12f);
    x[row * 64 + lane] = v * scale;
}

// ---------------- graph conv: atomic scatter ----------------
// out[c] += dinv[r]*dinv[c] * xin[r]   for each directed edge (r,c)
__global__ void k_conv_scatter(const int* __restrict__ rows, const int* __restrict__ cols,
                               const float* __restrict__ dinv,
                               const float* __restrict__ xin, float* __restrict__ xout, int E) {
    int tid = blockIdx.x * blockDim.x + threadIdx.x;   // E*16 threads
    int e = tid >> 4;
    if (e >= E) return;
    int q = tid & 15;
    int r = rows[e];
    int c = cols[e];
    float w = dinv[r] * dinv[c];
    const float4 v = *reinterpret_cast<const float4*>(xin + (long)r * 64 + q * 4);
    float* dst = xout + (long)c * 64 + q * 4;
    atomicAdd(dst + 0, v.x * w);
    atomicAdd(dst + 1, v.y * w);
    atomicAdd(dst + 2, v.z * w);
    atomicAdd(dst + 3, v.w * w);
}

// ---------------- d_out = x + h (then conv2 atomically adds h1) ----------------
__global__ void k_add2(const float* __restrict__ a, const float* __restrict__ b,
                       float* __restrict__ out, int n4) {
    int i = blockIdx.x * blockDim.x + threadIdx.x;
    if (i >= n4) return;
    const float4 va = reinterpret_cast<const float4*>(a)[i];
    const float4 vb = reinterpret_cast<const float4*>(b)[i];
    float4 o = { va.x + vb.x, va.y + vb.y, va.z + vb.z, va.w + vb.w };
    reinterpret_cast<float4*>(out)[i] = o;
}

extern "C" void kernel_launch(void* const* d_in, const int* in_sizes, int n_in,
                              void* d_out, int out_size, void* d_ws, size_t ws_size,
                              hipStream_t stream) {
    const int*   edge_index = (const int*)d_in[1];
    const float* features   = (const float*)d_in[2];
    const float* preference = (const float*)d_in[3];
    const float* W1         = (const float*)d_in[4];
    const float* b1         = (const float*)d_in[5];
    const float* W2         = (const float*)d_in[6];
    const float* b2         = (const float*)d_in[7];

    const int E = in_sizes[1] / 2;                 // 4M directed edges
    const int* e_row = edge_index;
    const int* e_col = edge_index + E;

    // workspace layout (floats)
    float* ws   = (float*)d_ws;
    float* x    = ws;                               // NNODE*64  = 6.4M
    float* h    = ws + (size_t)NNODE * 64;          // NNODE*64  = 6.4M
    float* dinv = ws + (size_t)NNODE * 64 * 2;      // NNODE
    int*   cnt  = (int*)(ws + (size_t)NNODE * 64 * 2 + NNODE);   // NNODE
    float* mid  = ws + (size_t)NNODE * 64 * 2 + 2 * NNODE;       // N_ITEM*256 = 12.8M

    float* out_xhat = (float*)d_out;                         // NNODE*64
    float* out_pref = (float*)d_out + (size_t)NNODE * 64;    // N_USER*64

    // 1. zero counters and h
    hipMemsetAsync(cnt, 0, sizeof(int) * NNODE, stream);
    hipMemsetAsync(h, 0, sizeof(float) * (size_t)NNODE * 64, stream);

    // 2. degree + dinv
    k_count_deg<<<2048, 256, 0, stream>>>(e_row, cnt, E);
    k_dinv<<<(NNODE + 255) / 256, 256, 0, stream>>>(cnt, dinv, NNODE);

    // 3. MLP: mid = lrelu(features @ W1 + b1)   [50000 x 256]
    {
        dim3 grid(D_HID / 64, (N_ITEM + 63) / 64);
        k_gemm_bias<true><<<grid, 256, 0, stream>>>(features, W1, b1, mid,
                                                    N_ITEM, D_FEAT, D_HID, 0);
    }
    // 4. temp = mid @ W2 + b2 -> x rows N_USER..NNODE
    {
        dim3 grid(D_LAT / 64, (N_ITEM + 63) / 64);
        k_gemm_bias<false><<<grid, 256, 0, stream>>>(mid, W2, b2, x,
                                                     N_ITEM, D_HID, D_LAT, N_USER);
    }
    // 5. x rows 0..N_USER = preference
    hipMemcpyAsync(x, preference, sizeof(float) * (size_t)N_USER * 64,
                   hipMemcpyDeviceToDevice, stream);
    // 6. normalize rows of x
    k_normalize<<<(NNODE + 3) / 4, 256, 0, stream>>>(x, NNODE);

    // 7. h = conv(x)
    {
        long threads = (long)E * 16;
        k_conv_scatter<<<(threads + 255) / 256, 256, 0, stream>>>(e_row, e_col, dinv, x, h, E);
    }
    // 8. d_out = x + h
    k_add2<<<((NNODE * 64 / 4) + 255) / 256, 256, 0, stream>>>(x, h, out_xhat, NNODE * 64 / 4);
    // 9. d_out += conv(h)
    {
        long threads = (long)E * 16;
        k_conv_scatter<<<(threads + 255) / 256, 256, 0, stream>>>(e_row, e_col, dinv, h, out_xhat, E);
    }
    // 10. preference passthrough
    hipMemcpyAsync(out_pref, preference, sizeof(float) * (size_t)N_USER * 64,
                   hipMemcpyDeviceToDevice, stream);
}

// Round 2
// 1645.162 us; speedup vs baseline: 4.7724x; 4.7724x over previous
//
#include <hip/hip_runtime.h>
#include <hip/hip_bf16.h>

// Problem constants (match reference setup_inputs)
#define N_USER 50000
#define N_ITEM 50000
#define NNODE  100000          // N_USER + N_ITEM
#define D_LAT  64
#define D_HID  256             // 4 * D_LAT
#define D_FEAT 1280

// ---------------- degree ----------------
__global__ void k_count_deg(const int* __restrict__ rows, int* __restrict__ cnt, int E) {
    int i = blockIdx.x * blockDim.x + threadIdx.x;
    int stride = gridDim.x * blockDim.x;
    for (; i < E; i += stride) atomicAdd(&cnt[rows[i]], 1);
}

__global__ void k_dinv(const int* __restrict__ cnt, float* __restrict__ dinv, int n) {
    int i = blockIdx.x * blockDim.x + threadIdx.x;
    if (i < n) {
        int c = cnt[i];
        dinv[i] = (c > 0) ? rsqrtf((float)c) : 0.0f;
    }
}

// ---------------- block scan (1024 elems / block of 256 threads) ----------------
// writes INCLUSIVE per-block scan into ptr1[i] (== ptr[i+1] pre-offset), block sums into bsum
__global__ void k_scan_block(const int* __restrict__ cnt, int* __restrict__ ptr1,
                             int* __restrict__ bsum, int n) {
    __shared__ int lds[256];
    const int base = blockIdx.x * 1024;
    const int t = threadIdx.x;
    const int idx = base + t * 4;
    int v0 = 0, v1 = 0, v2 = 0, v3 = 0;
    if (idx + 0 < n) v0 = cnt[idx + 0];
    if (idx + 1 < n) v1 = cnt[idx + 1];
    if (idx + 2 < n) v2 = cnt[idx + 2];
    if (idx + 3 < n) v3 = cnt[idx + 3];
    lds[t] = v0 + v1 + v2 + v3;
    __syncthreads();
    for (int off = 1; off < 256; off <<= 1) {
        int val = lds[t];
        int add = (t >= off) ? lds[t - off] : 0;
        __syncthreads();
        lds[t] = val + add;
        __syncthreads();
    }
    int run = (t == 0) ? 0 : lds[t - 1];
    if (t == 255) bsum[blockIdx.x] = lds[255];
    if (idx + 0 < n) { run += v0; ptr1[idx + 0] = run; }
    if (idx + 1 < n) { run += v1; ptr1[idx + 1] = run; }
    if (idx + 2 < n) { run += v2; ptr1[idx + 2] = run; }
    if (idx + 3 < n) { run += v3; ptr1[idx + 3] = run; }
}

// serial exclusive scan of block sums (nb <= 128, trivial)
__global__ void k_scan_top(int* __restrict__ bsum, int nb) {
    if (threadIdx.x == 0 && blockIdx.x == 0) {
        int acc = 0;
        for (int i = 0; i < nb; ++i) { int v = bsum[i]; bsum[i] = acc; acc += v; }
    }
}

// finalize: ptr[i+1] = inclusive + block offset; cursor[i] = ptr[i] (exclusive)
__global__ void k_scan_apply(int* __restrict__ ptr1, int* __restrict__ cursor,
                             const int* __restrict__ cnt, const int* __restrict__ boff, int n) {
    int i = blockIdx.x * blockDim.x + threadIdx.x;
    if (i >= n) return;
    int f = ptr1[i] + boff[i >> 10];
    ptr1[i] = f;
    cursor[i] = f - cnt[i];
}

// ---------------- CSR build: scatter edges grouped by destination ----------------
__global__ void k_build_adj(const int* __restrict__ rows, const int* __restrict__ cols,
                            const float* __restrict__ dinv, int* __restrict__ cursor,
                            int* __restrict__ adj_src, float* __restrict__ adj_w, int E) {
    int i = blockIdx.x * blockDim.x + threadIdx.x;
    int stride = gridDim.x * blockDim.x;
    for (; i < E; i += stride) {
        int r = rows[i], c = cols[i];
        int pos = atomicAdd(&cursor[c], 1);
        adj_src[pos] = r;
        adj_w[pos] = dinv[r] * dinv[c];
    }
}

// ---------------- fp32 tiled GEMM with bias (+ optional leaky-relu) ----------------
template<bool LRELU>
__global__ void k_gemm_bias(const float* __restrict__ A, const float* __restrict__ B,
                            const float* __restrict__ bias, float* __restrict__ C,
                            int M, int K, int Nn, int row_off) {
    const int BM = 64, BN = 64, BK = 16;
    __shared__ float As[BK][BM + 1];
    __shared__ float Bs[BK][BN + 1];
    const int t  = threadIdx.x;            // 256 threads
    const int tx = t & 15;
    const int ty = t >> 4;
    const int bm = blockIdx.y * BM;
    const int bn = blockIdx.x * BN;

    float acc[4][4] = {};

    for (int k0 = 0; k0 < K; k0 += BK) {
        {
            const int kk = t & 15;
            const int mm = t >> 4;
            #pragma unroll
            for (int p = 0; p < 4; ++p) {
                int r = bm + mm + p * 16;
                float v = 0.0f;
                if (r < M) v = A[(long)r * K + k0 + kk];
                As[kk][mm + p * 16] = v;
            }
        }
        {
            const int nn = t & 63;
            const int kb = t >> 6;
            #pragma unroll
            for (int p = 0; p < 4; ++p) {
                Bs[kb + p * 4][nn] = B[(long)(k0 + kb + p * 4) * Nn + bn + nn];
            }
        }
        __syncthreads();
        #pragma unroll
        for (int kk = 0; kk < BK; ++kk) {
            float a[4], b[4];
            #pragma unroll
            for (int i = 0; i < 4; ++i) a[i] = As[kk][ty * 4 + i];
            #pragma unroll
            for (int j = 0; j < 4; ++j) b[j] = Bs[kk][tx * 4 + j];
            #pragma unroll
            for (int i = 0; i < 4; ++i)
                #pragma unroll
                for (int j = 0; j < 4; ++j)
                    acc[i][j] += a[i] * b[j];
        }
        __syncthreads();
    }

    #pragma unroll
    for (int i = 0; i < 4; ++i) {
        int r = bm + ty * 4 + i;
        if (r >= M) continue;
        #pragma unroll
        for (int j = 0; j < 4; ++j) {
            int n = bn + tx * 4 + j;
            float v = acc[i][j] + bias[n];
            if (LRELU) v = (v > 0.0f) ? v : 0.01f * v;
            C[(long)(row_off + r) * Nn + n] = v;
        }
    }
}

// ---------------- row normalize (64 lanes per row) ----------------
__global__ void k_normalize(float* __restrict__ x, int nrows) {
    int row  = blockIdx.x * (blockDim.x >> 6) + (threadIdx.x >> 6);
    int lane = threadIdx.x & 63;
    if (row >= nrows) return;
    float v = x[row * 64 + lane];
    float ss = v * v;
    #pragma unroll
    for (int off = 32; off > 0; off >>= 1) ss += __shfl_xor(ss, off, 64);
    float norm = sqrtf(ss);
    float scale = 1.0f / fmaxf(norm, 1e-12f);
    x[row * 64 + lane] = v * scale;
}

// ---------------- graph conv: CSR gather, one wave per node ----------------
// FUSE=false: xout[node] = sum_j w_j * xin[src_j]
// FUSE=true : xout[node] = addA[node] + xin[node]... no: out = a0 + a1 + gather
template<bool FUSE>
__global__ void k_conv_gather(const int* __restrict__ ptr, const int* __restrict__ adj_src,
                              const float* __restrict__ adj_w, const float* __restrict__ xin,
                              const float* __restrict__ a0, float* __restrict__ xout, int n) {
    int node = blockIdx.x * (blockDim.x >> 6) + (threadIdx.x >> 6);
    int lane = threadIdx.x & 63;
    if (node >= n) return;
    int beg = ptr[node], end = ptr[node + 1];
    float acc = 0.0f;
    int j = beg;
    for (; j + 4 <= end; j += 4) {
        int   s0 = adj_src[j + 0], s1 = adj_src[j + 1], s2 = adj_src[j + 2], s3 = adj_src[j + 3];
        float w0 = adj_w[j + 0],   w1 = adj_w[j + 1],   w2 = adj_w[j + 2],   w3 = adj_w[j + 3];
        float x0 = xin[(long)s0 * 64 + lane];
        float x1 = xin[(long)s1 * 64 + lane];
        float x2 = xin[(long)s2 * 64 + lane];
        float x3 = xin[(long)s3 * 64 + lane];
        acc += w0 * x0 + w1 * x1 + w2 * x2 + w3 * x3;
    }
    for (; j < end; ++j) acc += adj_w[j] * xin[(long)adj_src[j] * 64 + lane];
    long o = (long)node * 64 + lane;
    if (FUSE) acc += a0[o] + xin[o];   // out = x + h + conv(h), with a0=x, xin=h
    xout[o] = acc;
}

extern "C" void kernel_launch(void* const* d_in, const int* in_sizes, int n_in,
                              void* d_out, int out_size, void* d_ws, size_t ws_size,
                              hipStream_t stream) {
    const int*   edge_index = (const int*)d_in[1];
    const float* features   = (const float*)d_in[2];
    const float* preference = (const float*)d_in[3];
    const float* W1         = (const float*)d_in[4];
    const float* b1         = (const float*)d_in[5];
    const float* W2         = (const float*)d_in[6];
    const float* b2         = (const float*)d_in[7];

    const int E = in_sizes[1] / 2;                 // 4M directed edges
    const int* e_row = edge_index;
    const int* e_col = edge_index + E;

    // workspace layout (4-byte elements)
    float* ws     = (float*)d_ws;
    float* x      = ws;                                    // NNODE*64 = 6.4M
    float* h      = x + (size_t)NNODE * 64;                // NNODE*64 = 6.4M
    float* dinv   = h + (size_t)NNODE * 64;                // NNODE
    int*   cnt    = (int*)(dinv + NNODE);                  // NNODE
    int*   ptr    = cnt + NNODE;                           // NNODE+1
    int*   cursor = ptr + NNODE + 1;                       // NNODE
    int*   bsum   = cursor + NNODE;                        // 128
    float* mid    = (float*)(bsum + 128);                  // N_ITEM*256 = 12.8M
    // adj arrays reuse mid's space (mid is dead after GEMM2)
    int*   adj_src = (int*)mid;                            // E
    float* adj_w   = mid + E;                              // E  (E*2 = 8M <= 12.8M)

    float* out_xhat = (float*)d_out;                       // NNODE*64
    float* out_pref = (float*)d_out + (size_t)NNODE * 64;  // N_USER*64

    const int nscan_blocks = (NNODE + 1023) / 1024;        // 98

    // --- degree / dinv ---
    hipMemsetAsync(cnt, 0, sizeof(int) * NNODE, stream);
    k_count_deg<<<2048, 256, 0, stream>>>(e_row, cnt, E);
    k_dinv<<<(NNODE + 255) / 256, 256, 0, stream>>>(cnt, dinv, NNODE);

    // --- MLP (uses mid; must finish before adj build reuses that space) ---
    {
        dim3 grid(D_HID / 64, (N_ITEM + 63) / 64);
        k_gemm_bias<true><<<grid, 256, 0, stream>>>(features, W1, b1, mid,
                                                    N_ITEM, D_FEAT, D_HID, 0);
    }
    {
        dim3 grid(D_LAT / 64, (N_ITEM + 63) / 64);
        k_gemm_bias<false><<<grid, 256, 0, stream>>>(mid, W2, b2, x,
                                                     N_ITEM, D_HID, D_LAT, N_USER);
    }
    hipMemcpyAsync(x, preference, sizeof(float) * (size_t)N_USER * 64,
                   hipMemcpyDeviceToDevice, stream);
    k_normalize<<<(NNODE + 3) / 4, 256, 0, stream>>>(x, NNODE);

    // --- CSR build (grouped by destination col; in/out degree equal by symmetry) ---
    hipMemsetAsync(ptr, 0, sizeof(int), stream);           // ptr[0] = 0
    k_scan_block<<<nscan_blocks, 256, 0, stream>>>(cnt, ptr + 1, bsum, NNODE);
    k_scan_top<<<1, 64, 0, stream>>>(bsum, nscan_blocks);
    k_scan_apply<<<(NNODE + 255) / 256, 256, 0, stream>>>(ptr + 1, cursor, cnt, bsum, NNODE);
    k_build_adj<<<2048, 256, 0, stream>>>(e_row, e_col, dinv, cursor, adj_src, adj_w, E);

    // --- conv1: h = conv(x) ---
    k_conv_gather<false><<<(NNODE + 3) / 4, 256, 0, stream>>>(ptr, adj_src, adj_w, x,
                                                              nullptr, h, NNODE);
    // --- conv2 fused epilogue: out = x + h + conv(h) ---
    k_conv_gather<true><<<(NNODE + 3) / 4, 256, 0, stream>>>(ptr, adj_src, adj_w, h,
                                                             x, out_xhat, NNODE);
    // --- preference passthrough ---
    hipMemcpyAsync(out_pref, preference, sizeof(float) * (size_t)N_USER * 64,
                   hipMemcpyDeviceToDevice, stream);
}

// Round 3
// 976.321 us; speedup vs baseline: 8.0418x; 1.6851x over previous
//
#include <hip/hip_runtime.h>
#include <hip/hip_bf16.h>

// Problem constants (match reference setup_inputs)
#define N_USER 50000
#define N_ITEM 50000
#define NNODE  100000          // N_USER + N_ITEM
#define D_LAT  64
#define D_HID  256             // 4 * D_LAT
#define D_FEAT 1280

typedef __attribute__((ext_vector_type(8))) short    bf16x8;
typedef __attribute__((ext_vector_type(4))) float    f32x4;
typedef __attribute__((ext_vector_type(4))) float    float4v;
typedef __attribute__((ext_vector_type(4))) unsigned short ushort4v;
typedef __attribute__((ext_vector_type(8))) unsigned short ushort8v;

__device__ __forceinline__ unsigned short f2bf(float f) {
    unsigned u = __builtin_bit_cast(unsigned, f);
    u += 0x7FFFu + ((u >> 16) & 1u);          // round-to-nearest-even
    return (unsigned short)(u >> 16);
}

// ---------------- degree ----------------
__global__ void k_count_deg(const int* __restrict__ rows, int* __restrict__ cnt, int E) {
    int i = blockIdx.x * blockDim.x + threadIdx.x;
    int stride = gridDim.x * blockDim.x;
    for (; i < E; i += stride) atomicAdd(&cnt[rows[i]], 1);
}

__global__ void k_dinv(const int* __restrict__ cnt, float* __restrict__ dinv, int n) {
    int i = blockIdx.x * blockDim.x + threadIdx.x;
    if (i < n) {
        int c = cnt[i];
        dinv[i] = (c > 0) ? rsqrtf((float)c) : 0.0f;
    }
}

// ---------------- block scan (1024 elems / block of 256 threads) ----------------
__global__ void k_scan_block(const int* __restrict__ cnt, int* __restrict__ ptr1,
                             int* __restrict__ bsum, int n) {
    __shared__ int lds[256];
    const int base = blockIdx.x * 1024;
    const int t = threadIdx.x;
    const int idx = base + t * 4;
    int v0 = 0, v1 = 0, v2 = 0, v3 = 0;
    if (idx + 0 < n) v0 = cnt[idx + 0];
    if (idx + 1 < n) v1 = cnt[idx + 1];
    if (idx + 2 < n) v2 = cnt[idx + 2];
    if (idx + 3 < n) v3 = cnt[idx + 3];
    lds[t] = v0 + v1 + v2 + v3;
    __syncthreads();
    for (int off = 1; off < 256; off <<= 1) {
        int val = lds[t];
        int add = (t >= off) ? lds[t - off] : 0;
        __syncthreads();
        lds[t] = val + add;
        __syncthreads();
    }
    int run = (t == 0) ? 0 : lds[t - 1];
    if (t == 255) bsum[blockIdx.x] = lds[255];
    if (idx + 0 < n) { run += v0; ptr1[idx + 0] = run; }
    if (idx + 1 < n) { run += v1; ptr1[idx + 1] = run; }
    if (idx + 2 < n) { run += v2; ptr1[idx + 2] = run; }
    if (idx + 3 < n) { run += v3; ptr1[idx + 3] = run; }
}

__global__ void k_scan_top(int* __restrict__ bsum, int nb) {
    if (threadIdx.x == 0 && blockIdx.x == 0) {
        int acc = 0;
        for (int i = 0; i < nb; ++i) { int v = bsum[i]; bsum[i] = acc; acc += v; }
    }
}

__global__ void k_scan_apply(int* __restrict__ ptr1, int* __restrict__ cursor,
                             const int* __restrict__ cnt, const int* __restrict__ boff, int n) {
    int i = blockIdx.x * blockDim.x + threadIdx.x;
    if (i >= n) return;
    int f = ptr1[i] + boff[i >> 10];
    ptr1[i] = f;
    cursor[i] = f - cnt[i];
}

// ---------------- CSR build ----------------
__global__ void k_build_adj(const int* __restrict__ rows, const int* __restrict__ cols,
                            const float* __restrict__ dinv, int* __restrict__ cursor,
                            int* __restrict__ adj_src, float* __restrict__ adj_w, int E) {
    int i = blockIdx.x * blockDim.x + threadIdx.x;
    int stride = gridDim.x * blockDim.x;
    for (; i < E; i += stride) {
        int r = rows[i], c = cols[i];
        int pos = atomicAdd(&cursor[c], 1);
        adj_src[pos] = r;
        adj_w[pos] = dinv[r] * dinv[c];
    }
}

// ---------------- W transpose+cast: Wt[n][k] = bf16(W[k][n]) ----------------
__global__ void k_transpose_cast(const float* __restrict__ W, unsigned short* __restrict__ Wt,
                                 int K, int Nn) {
    int k = blockIdx.x * 256 + threadIdx.x;
    int n = blockIdx.y;
    if (k < K) Wt[(size_t)n * K + k] = f2bf(W[(size_t)k * Nn + n]);
}

// ---------------- bf16 MFMA GEMM ----------------
// C[row][col] = act( sum_k A[row][k] * Bt[col][k] + bias[col] )
// A: fp32 (cast on stage) or bf16; Bt: bf16 [N][K]; block = 256 thr = 4 waves.
// WM x WN wave layout, each wave computes a 64x64 tile; BM = WM*64, N = WN*64.
template<int WM, int WN, bool AF32, bool LRELU, bool OUTBF16>
__global__ __launch_bounds__(256)
void k_mfma_gemm(const void* __restrict__ Araw, const unsigned short* __restrict__ Bt,
                 const float* __restrict__ bias, void* __restrict__ Craw,
                 int M, int K, int ldc, int row_off) {
    constexpr int BM = WM * 64;
    __shared__ __align__(16) char lds[BM * 128];   // BM rows x 64 bf16 (XOR-swizzled)
    const int t    = threadIdx.x;
    const int lane = t & 63;
    const int wave = t >> 6;
    const int wm   = (WN == 1) ? wave : 0;
    const int wn   = (WN == 1) ? 0 : wave;
    const int bm   = blockIdx.x * BM;

    f32x4 acc[4][4] = {};

    for (int k0 = 0; k0 < K; k0 += 64) {
        // ---- stage A tile [BM][64] bf16 into LDS, XOR-swizzled ----
        #pragma unroll
        for (int p = 0; p < WM; ++p) {
            int c    = t + p * 256;
            int r    = c >> 2;              // 0..BM-1
            int kc   = (c & 3) * 16;        // elem offset in BK
            int grow = bm + r;
            int lb   = r * 128 + kc * 2;    // byte offset
            int swz  = (r & 7) << 4;
            if (AF32) {
                const float* Ar = (const float*)Araw + (size_t)grow * K + k0 + kc;
                #pragma unroll
                for (int j = 0; j < 4; ++j) {
                    float4v v = (float4v)0.0f;
                    if (grow < M) v = *(const float4v*)(Ar + j * 4);
                    ushort4v u;
                    u[0] = f2bf(v[0]); u[1] = f2bf(v[1]);
                    u[2] = f2bf(v[2]); u[3] = f2bf(v[3]);
                    *(ushort4v*)(lds + ((lb + j * 8) ^ swz)) = u;
                }
            } else {
                const unsigned short* Ar = (const unsigned short*)Araw + (size_t)grow * K + k0 + kc;
                ushort8v w0 = (ushort8v)0, w1 = (ushort8v)0;
                if (grow < M) {
                    w0 = *(const ushort8v*)(Ar);
                    w1 = *(const ushort8v*)(Ar + 8);
                }
                *(ushort8v*)(lds + ((lb +  0) ^ swz)) = w0;
                *(ushort8v*)(lds + ((lb + 16) ^ swz)) = w1;
            }
        }
        __syncthreads();
        // ---- 2 k-steps of 32 ----
        #pragma unroll
        for (int ks = 0; ks < 2; ++ks) {
            bf16x8 a[4], b[4];
            #pragma unroll
            for (int fm = 0; fm < 4; ++fm) {
                int r = wm * 64 + fm * 16 + (lane & 15);
                int byte = r * 128 + (ks * 32 + (lane >> 4) * 8) * 2;
                a[fm] = *(const bf16x8*)(lds + (byte ^ ((r & 7) << 4)));
            }
            #pragma unroll
            for (int fn = 0; fn < 4; ++fn) {
                int col = wn * 64 + fn * 16 + (lane & 15);
                b[fn] = *(const bf16x8*)(Bt + (size_t)col * K + k0 + ks * 32 + (lane >> 4) * 8);
            }
            #pragma unroll
            for (int fm = 0; fm < 4; ++fm)
                #pragma unroll
                for (int fn = 0; fn < 4; ++fn)
                    acc[fm][fn] = __builtin_amdgcn_mfma_f32_16x16x32_bf16(a[fm], b[fn], acc[fm][fn], 0, 0, 0);
        }
        __syncthreads();
    }

    // ---- epilogue ----
    #pragma unroll
    for (int fm = 0; fm < 4; ++fm) {
        #pragma unroll
        for (int fn = 0; fn < 4; ++fn) {
            int colg = wn * 64 + fn * 16 + (lane & 15);
            float bb = bias[colg];
            #pragma unroll
            for (int reg = 0; reg < 4; ++reg) {
                int rowg = bm + wm * 64 + fm * 16 + (lane >> 4) * 4 + reg;
                if (rowg >= M) continue;
                float o = acc[fm][fn][reg] + bb;
                if (LRELU) o = (o > 0.0f) ? o : 0.01f * o;
                if (OUTBF16) {
                    ((unsigned short*)Craw)[(size_t)(row_off + rowg) * ldc + colg] = f2bf(o);
                } else {
                    ((float*)Craw)[(size_t)(row_off + rowg) * ldc + colg] = o;
                }
            }
        }
    }
}

// ---------------- row normalize (64 lanes per row) ----------------
__global__ void k_normalize(float* __restrict__ x, int nrows) {
    int row  = blockIdx.x * (blockDim.x >> 6) + (threadIdx.x >> 6);
    int lane = threadIdx.x & 63;
    if (row >= nrows) return;
    float v = x[row * 64 + lane];
    float ss = v * v;
    #pragma unroll
    for (int off = 32; off > 0; off >>= 1) ss += __shfl_xor(ss, off, 64);
    float norm = sqrtf(ss);
    float scale = 1.0f / fmaxf(norm, 1e-12f);
    x[row * 64 + lane] = v * scale;
}

// ---------------- graph conv: CSR gather, one wave per node ----------------
template<bool FUSE>
__global__ void k_conv_gather(const int* __restrict__ ptr, const int* __restrict__ adj_src,
                              const float* __restrict__ adj_w, const float* __restrict__ xin,
                              const float* __restrict__ a0, float* __restrict__ xout, int n) {
    int node = blockIdx.x * (blockDim.x >> 6) + (threadIdx.x >> 6);
    int lane = threadIdx.x & 63;
    if (node >= n) return;
    int beg = ptr[node], end = ptr[node + 1];
    float acc = 0.0f;
    int j = beg;
    for (; j + 4 <= end; j += 4) {
        int   s0 = adj_src[j + 0], s1 = adj_src[j + 1], s2 = adj_src[j + 2], s3 = adj_src[j + 3];
        float w0 = adj_w[j + 0],   w1 = adj_w[j + 1],   w2 = adj_w[j + 2],   w3 = adj_w[j + 3];
        float x0 = xin[(long)s0 * 64 + lane];
        float x1 = xin[(long)s1 * 64 + lane];
        float x2 = xin[(long)s2 * 64 + lane];
        float x3 = xin[(long)s3 * 64 + lane];
        acc += w0 * x0 + w1 * x1 + w2 * x2 + w3 * x3;
    }
    for (; j < end; ++j) acc += adj_w[j] * xin[(long)adj_src[j] * 64 + lane];
    long o = (long)node * 64 + lane;
    if (FUSE) acc += a0[o] + xin[o];   // out = x + h + conv(h), with a0=x, xin=h
    xout[o] = acc;
}

extern "C" void kernel_launch(void* const* d_in, const int* in_sizes, int n_in,
                              void* d_out, int out_size, void* d_ws, size_t ws_size,
                              hipStream_t stream) {
    const int*   edge_index = (const int*)d_in[1];
    const float* features   = (const float*)d_in[2];
    const float* preference = (const float*)d_in[3];
    const float* W1         = (const float*)d_in[4];
    const float* b1         = (const float*)d_in[5];
    const float* W2         = (const float*)d_in[6];
    const float* b2         = (const float*)d_in[7];

    const int E = in_sizes[1] / 2;                 // 4M directed edges
    const int* e_row = edge_index;
    const int* e_col = edge_index + E;

    // workspace layout (4-byte units)
    float* ws     = (float*)d_ws;
    float* x      = ws;                                    // NNODE*64 = 6.4M
    float* h      = x + (size_t)NNODE * 64;                // NNODE*64 = 6.4M
    float* dinv   = h + (size_t)NNODE * 64;                // NNODE
    int*   cnt    = (int*)(dinv + NNODE);                  // NNODE
    int*   ptr    = cnt + NNODE;                           // NNODE+1
    int*   cursor = ptr + NNODE + 1;                       // NNODE
    int*   bsum   = cursor + NNODE;                        // 128
    float* regionR = (float*)(bsum + 128);                 // shared region, 8M units
    // MLP phase (dead after GEMM2):
    unsigned short* midb = (unsigned short*)regionR;                 // N_ITEM*256 bf16 (6.4M units)
    unsigned short* W1t  = midb + (size_t)N_ITEM * D_HID;            // 256*1280 bf16
    unsigned short* W2t  = W1t + (size_t)D_HID * D_FEAT;             // 64*256 bf16
    // Graph phase (overlays MLP phase):
    int*   adj_src = (int*)regionR;                        // E (4M)
    float* adj_w   = regionR + E;                          // E (4M)

    float* out_xhat = (float*)d_out;                       // NNODE*64
    float* out_pref = (float*)d_out + (size_t)NNODE * 64;  // N_USER*64

    const int nscan_blocks = (NNODE + 1023) / 1024;        // 98

    // --- degree / dinv ---
    hipMemsetAsync(cnt, 0, sizeof(int) * NNODE, stream);
    k_count_deg<<<2048, 256, 0, stream>>>(e_row, cnt, E);
    k_dinv<<<(NNODE + 255) / 256, 256, 0, stream>>>(cnt, dinv, NNODE);

    // --- weight transpose + cast ---
    {
        dim3 g1((D_FEAT + 255) / 256, D_HID);
        k_transpose_cast<<<g1, 256, 0, stream>>>(W1, W1t, D_FEAT, D_HID);
        dim3 g2(1, D_LAT);
        k_transpose_cast<<<g2, 256, 0, stream>>>(W2, W2t, D_HID, D_LAT);
    }

    // --- GEMM1: midb = bf16(lrelu(features @ W1 + b1))  [50000 x 256] ---
    k_mfma_gemm<1, 4, true, true, true><<<(N_ITEM + 63) / 64, 256, 0, stream>>>(
        features, W1t, b1, midb, N_ITEM, D_FEAT, D_HID, 0);

    // --- GEMM2: x[N_USER..] = midb @ W2 + b2  [50000 x 64] fp32 ---
    k_mfma_gemm<4, 1, false, false, false><<<(N_ITEM + 255) / 256, 256, 0, stream>>>(
        midb, W2t, b2, x, N_ITEM, D_HID, D_LAT, N_USER);

    // --- x rows 0..N_USER = preference; normalize all rows ---
    hipMemcpyAsync(x, preference, sizeof(float) * (size_t)N_USER * 64,
                   hipMemcpyDeviceToDevice, stream);
    k_normalize<<<(NNODE + 3) / 4, 256, 0, stream>>>(x, NNODE);

    // --- CSR build (after GEMM2: regionR is free) ---
    hipMemsetAsync(ptr, 0, sizeof(int), stream);           // ptr[0] = 0
    k_scan_block<<<nscan_blocks, 256, 0, stream>>>(cnt, ptr + 1, bsum, NNODE);
    k_scan_top<<<1, 64, 0, stream>>>(bsum, nscan_blocks);
    k_scan_apply<<<(NNODE + 255) / 256, 256, 0, stream>>>(ptr + 1, cursor, cnt, bsum, NNODE);
    k_build_adj<<<2048, 256, 0, stream>>>(e_row, e_col, dinv, cursor, adj_src, adj_w, E);

    // --- conv1: h = conv(x) ---
    k_conv_gather<false><<<(NNODE + 3) / 4, 256, 0, stream>>>(ptr, adj_src, adj_w, x,
                                                              nullptr, h, NNODE);
    // --- conv2 fused epilogue: out = x + h + conv(h) ---
    k_conv_gather<true><<<(NNODE + 3) / 4, 256, 0, stream>>>(ptr, adj_src, adj_w, h,
                                                             x, out_xhat, NNODE);
    // --- preference passthrough ---
    hipMemcpyAsync(out_pref, preference, sizeof(float) * (size_t)N_USER * 64,
                   hipMemcpyDeviceToDevice, stream);
}

// Round 4
// 843.350 us; speedup vs baseline: 9.3097x; 1.1577x over previous
//
#include <hip/hip_runtime.h>
#include <hip/hip_bf16.h>

// Problem constants (match reference setup_inputs)
#define N_USER 50000
#define N_ITEM 50000
#define NNODE  100000          // N_USER + N_ITEM
#define D_LAT  64
#define D_HID  256             // 4 * D_LAT
#define D_FEAT 1280

typedef __attribute__((ext_vector_type(8))) short    bf16x8;
typedef __attribute__((ext_vector_type(4))) float    f32x4;
typedef __attribute__((ext_vector_type(4))) float    float4v;
typedef __attribute__((ext_vector_type(4))) unsigned short ushort4v;
typedef __attribute__((ext_vector_type(8))) unsigned short ushort8v;

__device__ __forceinline__ unsigned short f2bf(float f) {
    unsigned u = __builtin_bit_cast(unsigned, f);
    u += 0x7FFFu + ((u >> 16) & 1u);          // round-to-nearest-even
    return (unsigned short)(u >> 16);
}
__device__ __forceinline__ float bf2f(unsigned short u) {
    return __builtin_bit_cast(float, ((unsigned)u) << 16);
}

// ---------------- degree ----------------
__global__ void k_count_deg(const int* __restrict__ rows, int* __restrict__ cnt, int E) {
    int i = blockIdx.x * blockDim.x + threadIdx.x;
    int stride = gridDim.x * blockDim.x;
    for (; i < E; i += stride) atomicAdd(&cnt[rows[i]], 1);
}

__global__ void k_dinv(const int* __restrict__ cnt, float* __restrict__ dinv, int n) {
    int i = blockIdx.x * blockDim.x + threadIdx.x;
    if (i < n) {
        int c = cnt[i];
        dinv[i] = (c > 0) ? rsqrtf((float)c) : 0.0f;
    }
}

// ---------------- block scan (1024 elems / block of 256 threads) ----------------
__global__ void k_scan_block(const int* __restrict__ cnt, int* __restrict__ ptr1,
                             int* __restrict__ bsum, int n) {
    __shared__ int lds[256];
    const int base = blockIdx.x * 1024;
    const int t = threadIdx.x;
    const int idx = base + t * 4;
    int v0 = 0, v1 = 0, v2 = 0, v3 = 0;
    if (idx + 0 < n) v0 = cnt[idx + 0];
    if (idx + 1 < n) v1 = cnt[idx + 1];
    if (idx + 2 < n) v2 = cnt[idx + 2];
    if (idx + 3 < n) v3 = cnt[idx + 3];
    lds[t] = v0 + v1 + v2 + v3;
    __syncthreads();
    for (int off = 1; off < 256; off <<= 1) {
        int val = lds[t];
        int add = (t >= off) ? lds[t - off] : 0;
        __syncthreads();
        lds[t] = val + add;
        __syncthreads();
    }
    int run = (t == 0) ? 0 : lds[t - 1];
    if (t == 255) bsum[blockIdx.x] = lds[255];
    if (idx + 0 < n) { run += v0; ptr1[idx + 0] = run; }
    if (idx + 1 < n) { run += v1; ptr1[idx + 1] = run; }
    if (idx + 2 < n) { run += v2; ptr1[idx + 2] = run; }
    if (idx + 3 < n) { run += v3; ptr1[idx + 3] = run; }
}

__global__ void k_scan_top(int* __restrict__ bsum, int nb) {
    if (threadIdx.x == 0 && blockIdx.x == 0) {
        int acc = 0;
        for (int i = 0; i < nb; ++i) { int v = bsum[i]; bsum[i] = acc; acc += v; }
    }
}

__global__ void k_scan_apply(int* __restrict__ ptr1, int* __restrict__ cursor,
                             const int* __restrict__ cnt, const int* __restrict__ boff, int n) {
    int i = blockIdx.x * blockDim.x + threadIdx.x;
    if (i >= n) return;
    int f = ptr1[i] + boff[i >> 10];
    ptr1[i] = f;
    cursor[i] = f - cnt[i];
}

// ---------------- CSR build: src index only (weights recomputed in gather) ----------------
__global__ void k_build_adj(const int* __restrict__ rows, const int* __restrict__ cols,
                            int* __restrict__ cursor, int* __restrict__ adj_src, int E) {
    int i = blockIdx.x * blockDim.x + threadIdx.x;
    int stride = gridDim.x * blockDim.x;
    for (; i < E; i += stride) {
        int r = rows[i], c = cols[i];
        int pos = atomicAdd(&cursor[c], 1);
        adj_src[pos] = r;
    }
}

// ---------------- W transpose+cast: Wt[n][k] = bf16(W[k][n]) ----------------
__global__ void k_transpose_cast(const float* __restrict__ W, unsigned short* __restrict__ Wt,
                                 int K, int Nn) {
    int k = blockIdx.x * 256 + threadIdx.x;
    int n = blockIdx.y;
    if (k < K) Wt[(size_t)n * K + k] = f2bf(W[(size_t)k * Nn + n]);
}

// ---------------- bf16 MFMA GEMM ----------------
// C[row][col] = act( sum_k A[row][k] * Bt[col][k] + bias[col] )
template<int WM, int WN, bool AF32, bool LRELU, bool OUTBF16>
__global__ __launch_bounds__(256)
void k_mfma_gemm(const void* __restrict__ Araw, const unsigned short* __restrict__ Bt,
                 const float* __restrict__ bias, void* __restrict__ Craw,
                 int M, int K, int ldc, int row_off) {
    constexpr int BM = WM * 64;
    __shared__ __align__(16) char lds[BM * 128];   // BM rows x 64 bf16 (XOR-swizzled)
    const int t    = threadIdx.x;
    const int lane = t & 63;
    const int wave = t >> 6;
    const int wm   = (WN == 1) ? wave : 0;
    const int wn   = (WN == 1) ? 0 : wave;
    const int bm   = blockIdx.x * BM;

    f32x4 acc[4][4] = {};

    for (int k0 = 0; k0 < K; k0 += 64) {
        #pragma unroll
        for (int p = 0; p < WM; ++p) {
            int c    = t + p * 256;
            int r    = c >> 2;              // 0..BM-1
            int kc   = (c & 3) * 16;        // elem offset in BK
            int grow = bm + r;
            int lb   = r * 128 + kc * 2;    // byte offset
            int swz  = (r & 7) << 4;
            if (AF32) {
                const float* Ar = (const float*)Araw + (size_t)grow * K + k0 + kc;
                #pragma unroll
                for (int j = 0; j < 4; ++j) {
                    float4v v = (float4v)0.0f;
                    if (grow < M) v = *(const float4v*)(Ar + j * 4);
                    ushort4v u;
                    u[0] = f2bf(v[0]); u[1] = f2bf(v[1]);
                    u[2] = f2bf(v[2]); u[3] = f2bf(v[3]);
                    *(ushort4v*)(lds + ((lb + j * 8) ^ swz)) = u;
                }
            } else {
                const unsigned short* Ar = (const unsigned short*)Araw + (size_t)grow * K + k0 + kc;
                ushort8v w0 = (ushort8v)0, w1 = (ushort8v)0;
                if (grow < M) {
                    w0 = *(const ushort8v*)(Ar);
                    w1 = *(const ushort8v*)(Ar + 8);
                }
                *(ushort8v*)(lds + ((lb +  0) ^ swz)) = w0;
                *(ushort8v*)(lds + ((lb + 16) ^ swz)) = w1;
            }
        }
        __syncthreads();
        #pragma unroll
        for (int ks = 0; ks < 2; ++ks) {
            bf16x8 a[4], b[4];
            #pragma unroll
            for (int fm = 0; fm < 4; ++fm) {
                int r = wm * 64 + fm * 16 + (lane & 15);
                int byte = r * 128 + (ks * 32 + (lane >> 4) * 8) * 2;
                a[fm] = *(const bf16x8*)(lds + (byte ^ ((r & 7) << 4)));
            }
            #pragma unroll
            for (int fn = 0; fn < 4; ++fn) {
                int col = wn * 64 + fn * 16 + (lane & 15);
                b[fn] = *(const bf16x8*)(Bt + (size_t)col * K + k0 + ks * 32 + (lane >> 4) * 8);
            }
            #pragma unroll
            for (int fm = 0; fm < 4; ++fm)
                #pragma unroll
                for (int fn = 0; fn < 4; ++fn)
                    acc[fm][fn] = __builtin_amdgcn_mfma_f32_16x16x32_bf16(a[fm], b[fn], acc[fm][fn], 0, 0, 0);
        }
        __syncthreads();
    }

    #pragma unroll
    for (int fm = 0; fm < 4; ++fm) {
        #pragma unroll
        for (int fn = 0; fn < 4; ++fn) {
            int colg = wn * 64 + fn * 16 + (lane & 15);
            float bb = bias[colg];
            #pragma unroll
            for (int reg = 0; reg < 4; ++reg) {
                int rowg = bm + wm * 64 + fm * 16 + (lane >> 4) * 4 + reg;
                if (rowg >= M) continue;
                float o = acc[fm][fn][reg] + bb;
                if (LRELU) o = (o > 0.0f) ? o : 0.01f * o;
                if (OUTBF16) {
                    ((unsigned short*)Craw)[(size_t)(row_off + rowg) * ldc + colg] = f2bf(o);
                } else {
                    ((float*)Craw)[(size_t)(row_off + rowg) * ldc + colg] = o;
                }
            }
        }
    }
}

// ---------------- row normalize (64 lanes per row), also emits bf16 copy ----------------
__global__ void k_normalize(float* __restrict__ x, unsigned short* __restrict__ xb, int nrows) {
    int row  = blockIdx.x * (blockDim.x >> 6) + (threadIdx.x >> 6);
    int lane = threadIdx.x & 63;
    if (row >= nrows) return;
    long o = (long)row * 64 + lane;
    float v = x[o];
    float ss = v * v;
    #pragma unroll
    for (int off = 32; off > 0; off >>= 1) ss += __shfl_xor(ss, off, 64);
    float norm = sqrtf(ss);
    float scale = 1.0f / fmaxf(norm, 1e-12f);
    float xv = v * scale;
    x[o]  = xv;
    xb[o] = f2bf(xv);
}

// ---------------- conv1: s = x + h (in place), hb = bf16(h); h = D^-1/2 A D^-1/2 x ----------------
__global__ void k_conv1(const int* __restrict__ ptr, const int* __restrict__ adj_src,
                        const float* __restrict__ dinv, const unsigned short* __restrict__ xb,
                        float* __restrict__ x, unsigned short* __restrict__ hb, int n) {
    int node = blockIdx.x * (blockDim.x >> 6) + (threadIdx.x >> 6);
    int lane = threadIdx.x & 63;
    if (node >= n) return;
    int beg = ptr[node], end = ptr[node + 1];
    float acc = 0.0f;
    int j = beg;
    for (; j + 4 <= end; j += 4) {
        int s0 = adj_src[j + 0], s1 = adj_src[j + 1], s2 = adj_src[j + 2], s3 = adj_src[j + 3];
        float w0 = dinv[s0], w1 = dinv[s1], w2 = dinv[s2], w3 = dinv[s3];
        float x0 = bf2f(xb[(long)s0 * 64 + lane]);
        float x1 = bf2f(xb[(long)s1 * 64 + lane]);
        float x2 = bf2f(xb[(long)s2 * 64 + lane]);
        float x3 = bf2f(xb[(long)s3 * 64 + lane]);
        acc += w0 * x0 + w1 * x1 + w2 * x2 + w3 * x3;
    }
    for (; j < end; ++j) acc += dinv[adj_src[j]] * bf2f(xb[(long)adj_src[j] * 64 + lane]);
    float hval = dinv[node] * acc;
    long o = (long)node * 64 + lane;
    x[o]  = x[o] + hval;          // s = x + h
    hb[o] = f2bf(hval);
}

// ---------------- conv2: out = s + D^-1/2 A D^-1/2 h ----------------
__global__ void k_conv2(const int* __restrict__ ptr, const int* __restrict__ adj_src,
                        const float* __restrict__ dinv, const unsigned short* __restrict__ hb,
                        const float* __restrict__ s, float* __restrict__ out, int n) {
    int node = blockIdx.x * (blockDim.x >> 6) + (threadIdx.x >> 6);
    int lane = threadIdx.x & 63;
    if (node >= n) return;
    int beg = ptr[node], end = ptr[node + 1];
    float acc = 0.0f;
    int j = beg;
    for (; j + 4 <= end; j += 4) {
        int s0 = adj_src[j + 0], s1 = adj_src[j + 1], s2 = adj_src[j + 2], s3 = adj_src[j + 3];
        float w0 = dinv[s0], w1 = dinv[s1], w2 = dinv[s2], w3 = dinv[s3];
        float x0 = bf2f(hb[(long)s0 * 64 + lane]);
        float x1 = bf2f(hb[(long)s1 * 64 + lane]);
        float x2 = bf2f(hb[(long)s2 * 64 + lane]);
        float x3 = bf2f(hb[(long)s3 * 64 + lane]);
        acc += w0 * x0 + w1 * x1 + w2 * x2 + w3 * x3;
    }
    for (; j < end; ++j) acc += dinv[adj_src[j]] * bf2f(hb[(long)adj_src[j] * 64 + lane]);
    long o = (long)node * 64 + lane;
    out[o] = s[o] + dinv[node] * acc;
}

extern "C" void kernel_launch(void* const* d_in, const int* in_sizes, int n_in,
                              void* d_out, int out_size, void* d_ws, size_t ws_size,
                              hipStream_t stream) {
    const int*   edge_index = (const int*)d_in[1];
    const float* features   = (const float*)d_in[2];
    const float* preference = (const float*)d_in[3];
    const float* W1         = (const float*)d_in[4];
    const float* b1         = (const float*)d_in[5];
    const float* W2         = (const float*)d_in[6];
    const float* b2         = (const float*)d_in[7];

    const int E = in_sizes[1] / 2;                 // 4M directed edges
    const int* e_row = edge_index;
    const int* e_col = edge_index + E;

    // workspace layout (4-byte units)
    float* ws     = (float*)d_ws;
    float* x      = ws;                                    // NNODE*64 = 6.4M units (x, then s=x+h)
    unsigned short* xb = (unsigned short*)(x + (size_t)NNODE * 64);   // NNODE*64 bf16 = 1.6M units
    unsigned short* hb = xb + (size_t)NNODE * 64;                     // NNODE*64 bf16 = 1.6M units
    float* dinv   = (float*)(hb + (size_t)NNODE * 64);     // NNODE
    int*   cnt    = (int*)(dinv + NNODE);                  // NNODE
    int*   ptr    = cnt + NNODE;                           // NNODE+1
    int*   cursor = ptr + NNODE + 1;                       // NNODE
    int*   bsum   = cursor + NNODE;                        // 128
    float* regionR = (float*)(bsum + 128);                 // shared region
    // MLP phase (dead after GEMM2):
    unsigned short* midb = (unsigned short*)regionR;                 // N_ITEM*256 bf16
    unsigned short* W1t  = midb + (size_t)N_ITEM * D_HID;            // 256*1280 bf16
    unsigned short* W2t  = W1t + (size_t)D_HID * D_FEAT;             // 64*256 bf16
    // Graph phase (overlays MLP phase):
    int*   adj_src = (int*)regionR;                        // E (4M units)

    float* out_xhat = (float*)d_out;                       // NNODE*64
    float* out_pref = (float*)d_out + (size_t)NNODE * 64;  // N_USER*64

    const int nscan_blocks = (NNODE + 1023) / 1024;        // 98

    // --- degree / dinv ---
    hipMemsetAsync(cnt, 0, sizeof(int) * NNODE, stream);
    k_count_deg<<<2048, 256, 0, stream>>>(e_row, cnt, E);
    k_dinv<<<(NNODE + 255) / 256, 256, 0, stream>>>(cnt, dinv, NNODE);

    // --- weight transpose + cast ---
    {
        dim3 g1((D_FEAT + 255) / 256, D_HID);
        k_transpose_cast<<<g1, 256, 0, stream>>>(W1, W1t, D_FEAT, D_HID);
        dim3 g2(1, D_LAT);
        k_transpose_cast<<<g2, 256, 0, stream>>>(W2, W2t, D_HID, D_LAT);
    }

    // --- GEMM1: midb = bf16(lrelu(features @ W1 + b1))  [50000 x 256] ---
    k_mfma_gemm<1, 4, true, true, true><<<(N_ITEM + 63) / 64, 256, 0, stream>>>(
        features, W1t, b1, midb, N_ITEM, D_FEAT, D_HID, 0);

    // --- GEMM2: x[N_USER..] = midb @ W2 + b2  [50000 x 64] fp32 ---
    k_mfma_gemm<4, 1, false, false, false><<<(N_ITEM + 255) / 256, 256, 0, stream>>>(
        midb, W2t, b2, x, N_ITEM, D_HID, D_LAT, N_USER);

    // --- x rows 0..N_USER = preference; normalize all rows (emit xb) ---
    hipMemcpyAsync(x, preference, sizeof(float) * (size_t)N_USER * 64,
                   hipMemcpyDeviceToDevice, stream);
    k_normalize<<<(NNODE + 3) / 4, 256, 0, stream>>>(x, xb, NNODE);

    // --- CSR build (after GEMM2: regionR is free) ---
    hipMemsetAsync(ptr, 0, sizeof(int), stream);           // ptr[0] = 0
    k_scan_block<<<nscan_blocks, 256, 0, stream>>>(cnt, ptr + 1, bsum, NNODE);
    k_scan_top<<<1, 64, 0, stream>>>(bsum, nscan_blocks);
    k_scan_apply<<<(NNODE + 255) / 256, 256, 0, stream>>>(ptr + 1, cursor, cnt, bsum, NNODE);
    k_build_adj<<<2048, 256, 0, stream>>>(e_row, e_col, cursor, adj_src, E);

    // --- conv1: x <- x + h ; hb = bf16(h) ---
    k_conv1<<<(NNODE + 3) / 4, 256, 0, stream>>>(ptr, adj_src, dinv, xb, x, hb, NNODE);
    // --- conv2: out = (x + h) + conv(h) ---
    k_conv2<<<(NNODE + 3) / 4, 256, 0, stream>>>(ptr, adj_src, dinv, hb, x, out_xhat, NNODE);
    // --- preference passthrough ---
    hipMemcpyAsync(out_pref, preference, sizeof(float) * (size_t)N_USER * 64,
                   hipMemcpyDeviceToDevice, stream);
}

// Round 6
// 838.284 us; speedup vs baseline: 9.3660x; 1.0060x over previous
//
#include <hip/hip_runtime.h>
#include <hip/hip_bf16.h>

// Problem constants (match reference setup_inputs)
#define N_USER 50000
#define N_ITEM 50000
#define NNODE  100000          // N_USER + N_ITEM
#define D_LAT  64
#define D_HID  256             // 4 * D_LAT
#define D_FEAT 1280
#define NXCD   8
#define NODES_PER_XCD (NNODE / NXCD)   // 12500

typedef __attribute__((ext_vector_type(8))) short    bf16x8;
typedef __attribute__((ext_vector_type(4))) float    f32x4;
typedef __attribute__((ext_vector_type(4))) float    float4v;
typedef __attribute__((ext_vector_type(4))) unsigned short ushort4v;
typedef __attribute__((ext_vector_type(8))) unsigned short ushort8v;

__device__ __forceinline__ unsigned short f2bf(float f) {
    unsigned u = __builtin_bit_cast(unsigned, f);
    u += 0x7FFFu + ((u >> 16) & 1u);          // round-to-nearest-even
    return (unsigned short)(u >> 16);
}
__device__ __forceinline__ float bf2f(unsigned short u) {
    return __builtin_bit_cast(float, ((unsigned)u) << 16);
}

// ---------------- degree: XCD-confined histogram ----------------
// blocks 8c..8c+7 scan chunk c; block keeps sources in its XCD's node range.
__global__ void k_count_deg_x(const int* __restrict__ rows, int* __restrict__ cnt,
                              int E, int CH) {
    const int xcd   = blockIdx.x & 7;
    const int chunk = blockIdx.x >> 3;
    const int lo    = xcd * NODES_PER_XCD;
    const int hi    = lo + NODES_PER_XCD;
    const int beg   = chunk * CH;
    const int end   = min(beg + CH, E);
    for (int i = beg + threadIdx.x; i < end; i += 256) {
        int r = rows[i];
        if (r >= lo && r < hi) atomicAdd(&cnt[r], 1);
    }
}

__global__ void k_dinv(const int* __restrict__ cnt, float* __restrict__ dinv, int n) {
    int i = blockIdx.x * blockDim.x + threadIdx.x;
    if (i < n) {
        int c = cnt[i];
        dinv[i] = (c > 0) ? rsqrtf((float)c) : 0.0f;
    }
}

// ---------------- block scan (1024 elems / block of 256 threads) ----------------
__global__ void k_scan_block(const int* __restrict__ cnt, int* __restrict__ ptr1,
                             int* __restrict__ bsum, int n) {
    __shared__ int lds[256];
    const int base = blockIdx.x * 1024;
    const int t = threadIdx.x;
    const int idx = base + t * 4;
    int v0 = 0, v1 = 0, v2 = 0, v3 = 0;
    if (idx + 0 < n) v0 = cnt[idx + 0];
    if (idx + 1 < n) v1 = cnt[idx + 1];
    if (idx + 2 < n) v2 = cnt[idx + 2];
    if (idx + 3 < n) v3 = cnt[idx + 3];
    lds[t] = v0 + v1 + v2 + v3;
    __syncthreads();
    for (int off = 1; off < 256; off <<= 1) {
        int val = lds[t];
        int add = (t >= off) ? lds[t - off] : 0;
        __syncthreads();
        lds[t] = val + add;
        __syncthreads();
    }
    int run = (t == 0) ? 0 : lds[t - 1];
    if (t == 255) bsum[blockIdx.x] = lds[255];
    if (idx + 0 < n) { run += v0; ptr1[idx + 0] = run; }
    if (idx + 1 < n) { run += v1; ptr1[idx + 1] = run; }
    if (idx + 2 < n) { run += v2; ptr1[idx + 2] = run; }
    if (idx + 3 < n) { run += v3; ptr1[idx + 3] = run; }
}

__global__ void k_scan_top(int* __restrict__ bsum, int nb) {
    if (threadIdx.x == 0 && blockIdx.x == 0) {
        int acc = 0;
        for (int i = 0; i < nb; ++i) { int v = bsum[i]; bsum[i] = acc; acc += v; }
    }
}

__global__ void k_scan_apply(int* __restrict__ ptr1, int* __restrict__ cursor,
                             const int* __restrict__ cnt, const int* __restrict__ boff, int n) {
    int i = blockIdx.x * blockDim.x + threadIdx.x;
    if (i >= n) return;
    int f = ptr1[i] + boff[i >> 10];
    ptr1[i] = f;
    cursor[i] = f - cnt[i];
}

// ---------------- CSR build: XCD-confined scatter (src index only) ----------------
__global__ void k_build_adj_x(const int* __restrict__ rows, const int* __restrict__ cols,
                              int* __restrict__ cursor, int* __restrict__ adj_src,
                              int E, int CH) {
    const int xcd   = blockIdx.x & 7;
    const int chunk = blockIdx.x >> 3;
    const int lo    = xcd * NODES_PER_XCD;
    const int hi    = lo + NODES_PER_XCD;
    const int beg   = chunk * CH;
    const int end   = min(beg + CH, E);
    for (int i = beg + threadIdx.x; i < end; i += 256) {
        int c = cols[i];
        if (c >= lo && c < hi) {
            int pos = atomicAdd(&cursor[c], 1);
            adj_src[pos] = rows[i];
        }
    }
}

// ---------------- W transpose+cast: Wt[n][k] = bf16(W[k][n]) ----------------
__global__ void k_transpose_cast(const float* __restrict__ W, unsigned short* __restrict__ Wt,
                                 int K, int Nn) {
    int k = blockIdx.x * 256 + threadIdx.x;
    int n = blockIdx.y;
    if (k < K) Wt[(size_t)n * K + k] = f2bf(W[(size_t)k * Nn + n]);
}

// ---------------- bf16 MFMA GEMM ----------------
// C[row][col] = act( sum_k A[row][k] * Bt[col][k] + bias[col] )
// NORM: row-normalize epilogue (requires WN==1 so each wave holds full rows),
//       writes fp32 C and bf16 xbOut.
template<int WM, int WN, bool AF32, bool LRELU, bool OUTBF16, bool NORM>
__global__ __launch_bounds__(256)
void k_mfma_gemm(const void* __restrict__ Araw, const unsigned short* __restrict__ Bt,
                 const float* __restrict__ bias, void* __restrict__ Craw,
                 unsigned short* __restrict__ xbOut,
                 int M, int K, int ldc, int row_off) {
    constexpr int BM = WM * 64;
    __shared__ __align__(16) char lds[BM * 128];   // BM rows x 64 bf16 (XOR-swizzled)
    const int t    = threadIdx.x;
    const int lane = t & 63;
    const int wave = t >> 6;
    const int wm   = (WN == 1) ? wave : 0;
    const int wn   = (WN == 1) ? 0 : wave;
    const int bm   = blockIdx.x * BM;

    f32x4 acc[4][4] = {};

    for (int k0 = 0; k0 < K; k0 += 64) {
        #pragma unroll
        for (int p = 0; p < WM; ++p) {
            int c    = t + p * 256;
            int r    = c >> 2;              // 0..BM-1
            int kc   = (c & 3) * 16;        // elem offset in BK
            int grow = bm + r;
            int lb   = r * 128 + kc * 2;    // byte offset
            int swz  = (r & 7) << 4;
            if (AF32) {
                const float* Ar = (const float*)Araw + (size_t)grow * K + k0 + kc;
                #pragma unroll
                for (int j = 0; j < 4; ++j) {
                    float4v v = (float4v)0.0f;
                    if (grow < M) v = *(const float4v*)(Ar + j * 4);
                    ushort4v u;
                    u[0] = f2bf(v[0]); u[1] = f2bf(v[1]);
                    u[2] = f2bf(v[2]); u[3] = f2bf(v[3]);
                    *(ushort4v*)(lds + ((lb + j * 8) ^ swz)) = u;
                }
            } else {
                const unsigned short* Ar = (const unsigned short*)Araw + (size_t)grow * K + k0 + kc;
                ushort8v w0 = (ushort8v)0, w1 = (ushort8v)0;
                if (grow < M) {
                    w0 = *(const ushort8v*)(Ar);
                    w1 = *(const ushort8v*)(Ar + 8);
                }
                *(ushort8v*)(lds + ((lb +  0) ^ swz)) = w0;
                *(ushort8v*)(lds + ((lb + 16) ^ swz)) = w1;
            }
        }
        __syncthreads();
        #pragma unroll
        for (int ks = 0; ks < 2; ++ks) {
            bf16x8 a[4], b[4];
            #pragma unroll
            for (int fm = 0; fm < 4; ++fm) {
                int r = wm * 64 + fm * 16 + (lane & 15);
                int byte = r * 128 + (ks * 32 + (lane >> 4) * 8) * 2;
                a[fm] = *(const bf16x8*)(lds + (byte ^ ((r & 7) << 4)));
            }
            #pragma unroll
            for (int fn = 0; fn < 4; ++fn) {
                int col = wn * 64 + fn * 16 + (lane & 15);
                b[fn] = *(const bf16x8*)(Bt + (size_t)col * K + k0 + ks * 32 + (lane >> 4) * 8);
            }
            #pragma unroll
            for (int fm = 0; fm < 4; ++fm)
                #pragma unroll
                for (int fn = 0; fn < 4; ++fn)
                    acc[fm][fn] = __builtin_amdgcn_mfma_f32_16x16x32_bf16(a[fm], b[fn], acc[fm][fn], 0, 0, 0);
        }
        __syncthreads();
    }

    if (NORM) {
        // Each wave holds complete rows (WN==1, ldc==64): cols = fn*16 + (lane&15).
        #pragma unroll
        for (int fm = 0; fm < 4; ++fm) {
            float o[4][4];   // [fn][reg]
            #pragma unroll
            for (int fn = 0; fn < 4; ++fn) {
                float bb = bias[fn * 16 + (lane & 15)];
                #pragma unroll
                for (int reg = 0; reg < 4; ++reg) o[fn][reg] = acc[fm][fn][reg] + bb;
            }
            #pragma unroll
            for (int reg = 0; reg < 4; ++reg) {
                float ss = o[0][reg] * o[0][reg] + o[1][reg] * o[1][reg]
                         + o[2][reg] * o[2][reg] + o[3][reg] * o[3][reg];
                ss += __shfl_xor(ss, 1, 64);
                ss += __shfl_xor(ss, 2, 64);
                ss += __shfl_xor(ss, 4, 64);
                ss += __shfl_xor(ss, 8, 64);
                float scale = 1.0f / fmaxf(sqrtf(ss), 1e-12f);
                int rowg = bm + wm * 64 + fm * 16 + (lane >> 4) * 4 + reg;
                if (rowg >= M) continue;
                size_t base = (size_t)(row_off + rowg) * 64 + (lane & 15);
                #pragma unroll
                for (int fn = 0; fn < 4; ++fn) {
                    float xv = o[fn][reg] * scale;
                    ((float*)Craw)[base + fn * 16] = xv;
                    xbOut[base + fn * 16] = f2bf(xv);
                }
            }
        }
    } else {
        #pragma unroll
        for (int fm = 0; fm < 4; ++fm) {
            #pragma unroll
            for (int fn = 0; fn < 4; ++fn) {
                int colg = wn * 64 + fn * 16 + (lane & 15);
                float bb = bias[colg];
                #pragma unroll
                for (int reg = 0; reg < 4; ++reg) {
                    int rowg = bm + wm * 64 + fm * 16 + (lane >> 4) * 4 + reg;
                    if (rowg >= M) continue;
                    float v = acc[fm][fn][reg] + bb;
                    if (LRELU) v = (v > 0.0f) ? v : 0.01f * v;
                    if (OUTBF16) {
                        ((unsigned short*)Craw)[(size_t)(row_off + rowg) * ldc + colg] = f2bf(v);
                    } else {
                        ((float*)Craw)[(size_t)(row_off + rowg) * ldc + colg] = v;
                    }
                }
            }
        }
    }
}

// ---------------- preference rows: normalize into x (fp32) + xb (bf16) ----------------
__global__ void k_norm_pref(const float* __restrict__ pref, float* __restrict__ x,
                            unsigned short* __restrict__ xb, int nrows) {
    int row  = blockIdx.x * (blockDim.x >> 6) + (threadIdx.x >> 6);
    int lane = threadIdx.x & 63;
    if (row >= nrows) return;
    long o = (long)row * 64 + lane;
    float v = pref[o];
    float ss = v * v;
    #pragma unroll
    for (int off = 32; off > 0; off >>= 1) ss += __shfl_xor(ss, off, 64);
    float scale = 1.0f / fmaxf(sqrtf(ss), 1e-12f);
    float xv = v * scale;
    x[o]  = xv;
    xb[o] = f2bf(xv);
}

// ---------------- conv1: s = x + h (in place), hb = bf16(h) ----------------
__global__ void k_conv1(const int* __restrict__ ptr, const int* __restrict__ adj_src,
                        const float* __restrict__ dinv, const unsigned short* __restrict__ xb,
                        float* __restrict__ x, unsigned short* __restrict__ hb, int n) {
    int node = blockIdx.x * (blockDim.x >> 6) + (threadIdx.x >> 6);
    int lane = threadIdx.x & 63;
    if (node >= n) return;
    int beg = ptr[node], end = ptr[node + 1];
    float acc = 0.0f;
    int j = beg;
    for (; j + 4 <= end; j += 4) {
        int s0 = adj_src[j + 0], s1 = adj_src[j + 1], s2 = adj_src[j + 2], s3 = adj_src[j + 3];
        float w0 = dinv[s0], w1 = dinv[s1], w2 = dinv[s2], w3 = dinv[s3];
        float x0 = bf2f(xb[(long)s0 * 64 + lane]);
        float x1 = bf2f(xb[(long)s1 * 64 + lane]);
        float x2 = bf2f(xb[(long)s2 * 64 + lane]);
        float x3 = bf2f(xb[(long)s3 * 64 + lane]);
        acc += w0 * x0 + w1 * x1 + w2 * x2 + w3 * x3;
    }
    for (; j < end; ++j) acc += dinv[adj_src[j]] * bf2f(xb[(long)adj_src[j] * 64 + lane]);
    float hval = dinv[node] * acc;
    long o = (long)node * 64 + lane;
    x[o]  = x[o] + hval;          // s = x + h
    hb[o] = f2bf(hval);
}

// ---------------- conv2: out = s + D^-1/2 A D^-1/2 h ----------------
__global__ void k_conv2(const int* __restrict__ ptr, const int* __restrict__ adj_src,
                        const float* __restrict__ dinv, const unsigned short* __restrict__ hb,
                        const float* __restrict__ s, float* __restrict__ out, int n) {
    int node = blockIdx.x * (blockDim.x >> 6) + (threadIdx.x >> 6);
    int lane = threadIdx.x & 63;
    if (node >= n) return;
    int beg = ptr[node], end = ptr[node + 1];
    float acc = 0.0f;
    int j = beg;
    for (; j + 4 <= end; j += 4) {
        int s0 = adj_src[j + 0], s1 = adj_src[j + 1], s2 = adj_src[j + 2], s3 = adj_src[j + 3];
        float w0 = dinv[s0], w1 = dinv[s1], w2 = dinv[s2], w3 = dinv[s3];
        float x0 = bf2f(hb[(long)s0 * 64 + lane]);
        float x1 = bf2f(hb[(long)s1 * 64 + lane]);
        float x2 = bf2f(hb[(long)s2 * 64 + lane]);
        float x3 = bf2f(hb[(long)s3 * 64 + lane]);
        acc += w0 * x0 + w1 * x1 + w2 * x2 + w3 * x3;
    }
    for (; j < end; ++j) acc += dinv[adj_src[j]] * bf2f(hb[(long)adj_src[j] * 64 + lane]);
    long o = (long)node * 64 + lane;
    out[o] = s[o] + dinv[node] * acc;
}

extern "C" void kernel_launch(void* const* d_in, const int* in_sizes, int n_in,
                              void* d_out, int out_size, void* d_ws, size_t ws_size,
                              hipStream_t stream) {
    const int*   edge_index = (const int*)d_in[1];
    const float* features   = (const float*)d_in[2];
    const float* preference = (const float*)d_in[3];
    const float* W1         = (const float*)d_in[4];
    const float* b1         = (const float*)d_in[5];
    const float* W2         = (const float*)d_in[6];
    const float* b2         = (const float*)d_in[7];

    const int E = in_sizes[1] / 2;                 // 4M directed edges
    const int* e_row = edge_index;
    const int* e_col = edge_index + E;

    // workspace layout (4-byte units)
    float* ws     = (float*)d_ws;
    float* x      = ws;                                    // NNODE*64 (x, then s=x+h)
    unsigned short* xb = (unsigned short*)(x + (size_t)NNODE * 64);   // NNODE*64 bf16
    unsigned short* hb = xb + (size_t)NNODE * 64;                     // NNODE*64 bf16
    float* dinv   = (float*)(hb + (size_t)NNODE * 64);     // NNODE
    int*   cnt    = (int*)(dinv + NNODE);                  // NNODE
    int*   ptr    = cnt + NNODE;                           // NNODE+1
    int*   cursor = ptr + NNODE + 1;                       // NNODE
    int*   bsum   = cursor + NNODE;                        // 128
    float* regionR = (float*)(bsum + 128);                 // shared region
    // MLP phase (dead after GEMM2):
    unsigned short* midb = (unsigned short*)regionR;                 // N_ITEM*256 bf16
    unsigned short* W1t  = midb + (size_t)N_ITEM * D_HID;            // 256*1280 bf16
    unsigned short* W2t  = W1t + (size_t)D_HID * D_FEAT;             // 64*256 bf16
    // Graph phase (overlays MLP phase):
    int*   adj_src = (int*)regionR;                        // E

    float* out_xhat = (float*)d_out;                       // NNODE*64
    float* out_pref = (float*)d_out + (size_t)NNODE * 64;  // N_USER*64

    const int nscan_blocks = (NNODE + 1023) / 1024;        // 98
    const int nchunks = 256;
    const int CH = (E + nchunks - 1) / nchunks;            // edges per chunk

    // --- degree / dinv (XCD-confined histogram) ---
    hipMemsetAsync(cnt, 0, sizeof(int) * NNODE, stream);
    k_count_deg_x<<<nchunks * NXCD, 256, 0, stream>>>(e_row, cnt, E, CH);
    k_dinv<<<(NNODE + 255) / 256, 256, 0, stream>>>(cnt, dinv, NNODE);

    // --- weight transpose + cast ---
    {
        dim3 g1((D_FEAT + 255) / 256, D_HID);
        k_transpose_cast<<<g1, 256, 0, stream>>>(W1, W1t, D_FEAT, D_HID);
        dim3 g2(1, D_LAT);
        k_transpose_cast<<<g2, 256, 0, stream>>>(W2, W2t, D_HID, D_LAT);
    }

    // --- GEMM1: midb = bf16(lrelu(features @ W1 + b1))  [50000 x 256] ---
    k_mfma_gemm<1, 4, true, true, true, false><<<(N_ITEM + 63) / 64, 256, 0, stream>>>(
        features, W1t, b1, midb, nullptr, N_ITEM, D_FEAT, D_HID, 0);

    // --- GEMM2 + fused normalize: x[N_USER..], xb[N_USER..] ---
    k_mfma_gemm<4, 1, false, false, false, true><<<(N_ITEM + 255) / 256, 256, 0, stream>>>(
        midb, W2t, b2, x, xb, N_ITEM, D_HID, D_LAT, N_USER);

    // --- preference rows: normalize into x + xb ---
    k_norm_pref<<<(N_USER + 3) / 4, 256, 0, stream>>>(preference, x, xb, N_USER);

    // --- CSR build (after GEMM2: regionR is free) ---
    hipMemsetAsync(ptr, 0, sizeof(int), stream);           // ptr[0] = 0
    k_scan_block<<<nscan_blocks, 256, 0, stream>>>(cnt, ptr + 1, bsum, NNODE);
    k_scan_top<<<1, 64, 0, stream>>>(bsum, nscan_blocks);
    k_scan_apply<<<(NNODE + 255) / 256, 256, 0, stream>>>(ptr + 1, cursor, cnt, bsum, NNODE);
    k_build_adj_x<<<nchunks * NXCD, 256, 0, stream>>>(e_row, e_col, cursor, adj_src, E, CH);

    // --- conv1: x <- x + h ; hb = bf16(h) ---
    k_conv1<<<(NNODE + 3) / 4, 256, 0, stream>>>(ptr, adj_src, dinv, xb, x, hb, NNODE);
    // --- conv2: out = (x + h) + conv(h) ---
    k_conv2<<<(NNODE + 3) / 4, 256, 0, stream>>>(ptr, adj_src, dinv, hb, x, out_xhat, NNODE);
    // --- preference passthrough ---
    hipMemcpyAsync(out_pref, preference, sizeof(float) * (size_t)N_USER * 64,
                   hipMemcpyDeviceToDevice, stream);
}